// Round 9
// baseline (258.926 us; speedup 1.0000x reference)
//
#include <hip/hip_runtime.h>
#include <hip/hip_bf16.h>

typedef __attribute__((ext_vector_type(8)))  __bf16 bf16x8;
typedef __attribute__((ext_vector_type(4)))  float  f32x4;

// Batched GEMM C[b] = A[b] @ B[b]^T, A/B:[8,4096,64] f32, C:[8,4096,4096] f32.
// R9: 16-row FULL-WIDTH band per block (16x4096 = 256KB out, 4 phases of
// 16x1024 staged in 64KB LDS). Each C row is written start-to-finish by ONE
// block in sequential 4KB wave-instruction runs; with batch-per-XCD swizzle
// each XCD sweeps its batch's C near-linearly (8 fillBuffer-like streams).
// Reads: B re-read 1MB/block -> 2GB total, all XCD-L2-local (A+B = 2MB/batch).
// MFMA 16x16x32 with SWAPPED operands: lane&15 = C-row, acc quad = 4
// consecutive C-cols -> b128 LDS writes; XOR swizzle ^((r&7)<<2) both sides.

static __device__ inline bf16x8 to_bf16x8(const float4& a, const float4& b) {
    bf16x8 r;
    r[0] = (__bf16)a.x; r[1] = (__bf16)a.y; r[2] = (__bf16)a.z; r[3] = (__bf16)a.w;
    r[4] = (__bf16)b.x; r[5] = (__bf16)b.y; r[6] = (__bf16)b.z; r[7] = (__bf16)b.w;
    return r;
}

__global__ __launch_bounds__(256) void MatrixAttention_76149770158251_kernel(
    const float* __restrict__ A, const float* __restrict__ Bm,
    float* __restrict__ C)
{
    const int N = 4096, D = 64;
    __shared__ float tile[16 * 1024];       // 64 KB: one 16x1024 phase

    // batch-per-XCD bijective swizzle (2048 blocks, 2048%8==0):
    // XCD k executes exactly batch k's 256 bands, in top-to-bottom order.
    const int lin  = blockIdx.x;
    const int swz  = (lin & 7) * 256 + (lin >> 3);
    const int bz   = swz >> 8;              // batch 0..7
    const int band = swz & 255;             // 0..255
    const int row0 = band * 16;

    const int lane = threadIdx.x & 63;
    const int wid  = threadIdx.x >> 6;      // 0..3: wave owns 256 cols/phase

    const float* __restrict__ Ab = A  + (size_t)bz * N * D;
    const float* __restrict__ Bb = Bm + (size_t)bz * N * D;
    float* __restrict__ Cb       = C  + (size_t)bz * N * N;

    const int fr = lane & 15;               // fragment row (0..15)
    const int kq = (lane >> 4) * 8;         // k sub-offset within 32-slice

    // A fragments: rows row0..row0+15, two K=32 slices (once per block)
    bf16x8 af[2];
#pragma unroll
    for (int h = 0; h < 2; ++h) {
        const float* p = Ab + (size_t)(row0 + fr) * D + h * 32 + kq;
        float4 v0 = *(const float4*)(p);
        float4 v1 = *(const float4*)(p + 4);
        af[h] = to_bf16x8(v0, v1);
    }

    for (int ph = 0; ph < 4; ++ph) {
        const int c0 = ph * 1024 + wid * 256;   // this wave's col base

        // 16 col-tiles of 16 cols; K=64 via 2 MFMA each.
        // SWAPPED operands: mfma(B_rows_frag, A_rows_frag) ->
        //   D: lane&15 = C-row (fr), reg quad = C-cols ct*16 + (lane>>4)*4 + r
#pragma unroll
        for (int ct = 0; ct < 16; ++ct) {
            f32x4 acc = (f32x4)0.0f;
#pragma unroll
            for (int h = 0; h < 2; ++h) {
                const float* p = Bb + (size_t)(c0 + ct * 16 + fr) * D + h * 32 + kq;
                float4 v0 = *(const float4*)(p);
                float4 v1 = *(const float4*)(p + 4);
                acc = __builtin_amdgcn_mfma_f32_16x16x32_bf16(
                    to_bf16x8(v0, v1), af[h], acc, 0, 0, 0);
            }
            // LDS stage (XOR-swizzled quad address, conflict-free b128)
            const int r     = fr;
            const int cbase = wid * 256 + ct * 16 + (lane >> 4) * 4;
            const int cswz  = cbase ^ ((r & 7) << 2);
            *(f32x4*)&tile[r * 1024 + cswz] = acc;
        }

        __syncthreads();

        // NT sweep: iteration it writes tile row 'it' as ONE contiguous 4KB
        // run in C (lane tid covers float4 tid of the row).
        float* Cbase = Cb + (size_t)row0 * N + ph * 1024;
#pragma unroll
        for (int it = 0; it < 16; ++it) {
            const int c4   = threadIdx.x;            // float4 index in row
            const int cswz = (c4 * 4) ^ ((it & 7) << 2);
            f32x4 v = *(const f32x4*)&tile[it * 1024 + cswz];
            __builtin_nontemporal_store(v, (f32x4*)(Cbase + (size_t)it * N + c4 * 4));
        }

        __syncthreads();                     // WAR: LDS reused next phase
    }
}

extern "C" void kernel_launch(void* const* d_in, const int* in_sizes, int n_in,
                              void* d_out, int out_size, void* d_ws, size_t ws_size,
                              hipStream_t stream) {
    const float* m1 = (const float*)d_in[0];
    const float* m2 = (const float*)d_in[1];
    float* out = (float*)d_out;

    dim3 grid(2048);
    dim3 block(256);
    MatrixAttention_76149770158251_kernel<<<grid, block, 0, stream>>>(m1, m2, out);
}

// Round 10
// 165.416 us; speedup vs baseline: 1.5653x; 1.5653x over previous
//
#include <hip/hip_runtime.h>
#include <hip/hip_bf16.h>

typedef __attribute__((ext_vector_type(8)))  __bf16 bf16x8;
typedef __attribute__((ext_vector_type(16))) float  f32x16;
typedef __attribute__((ext_vector_type(4)))  float  f32x4;   // for nt stores

// Batched GEMM C[b] = A[b] @ B[b]^T, A/B:[8,4096,64] f32, C:[8,4096,4096] f32.
// Model (fits R1-R9): HBM page ~1KB; write efficiency ~ run_length/1KB.
//   512B runs -> 3.47 TB/s observed (= 6.9/2 predicted). Linear fill: 6.9.
// R10 clean test: 64x256 tile -> every wave-instruction writes ONE FULL 1KB
// page (a complete row segment). Read ratio just 1.25:1 (+134MB L2 reads,
// ~+3us) so the R6/R9 read confound is controlled. All else identical to R5:
// 64KB LDS (2 resident blocks), NT dwordx4 sweep, verified D-layout.

static __device__ inline bf16x8 to_bf16x8(const float4& a, const float4& b) {
    bf16x8 r;
    r[0] = (__bf16)a.x; r[1] = (__bf16)a.y; r[2] = (__bf16)a.z; r[3] = (__bf16)a.w;
    r[4] = (__bf16)b.x; r[5] = (__bf16)b.y; r[6] = (__bf16)b.z; r[7] = (__bf16)b.w;
    return r;
}

__global__ __launch_bounds__(256) void MatrixAttention_76149770158251_kernel(
    const float* __restrict__ A, const float* __restrict__ Bm,
    float* __restrict__ C)
{
    const int N = 4096, D = 64;
    __shared__ float tile[64 * 256];        // 64 KB C-tile staging

    const int lane = threadIdx.x & 63;
    const int wid  = threadIdx.x >> 6;      // 0..3
    const int wr   = wid >> 1;              // wave = 32 rows x 128 cols
    const int wc   = wid & 1;
    const int bz   = blockIdx.z;

    const int brow = blockIdx.y * 64;
    const int bcol = blockIdx.x * 256;
    const int row0 = brow + wr * 32;
    const int col0 = bcol + wc * 128;

    const float* __restrict__ Ab = A  + (size_t)bz * N * D;
    const float* __restrict__ Bb = Bm + (size_t)bz * N * D;
    float* __restrict__ Cb       = C  + (size_t)bz * N * N;

    const int lrow  = lane & 31;            // row within 32-frag
    const int khalf = (lane >> 5) * 8;      // 0 or 8: K slice

    // A fragments: this wave's 32 rows, 4 K-steps
    bf16x8 af[4];
#pragma unroll
    for (int ks = 0; ks < 4; ++ks) {
        const float* p = Ab + (size_t)(row0 + lrow) * D + ks * 16 + khalf;
        float4 v0 = *(const float4*)(p);
        float4 v1 = *(const float4*)(p + 4);
        af[ks] = to_bf16x8(v0, v1);
    }

    // 4 col-frags of 32 cols: load B inline, MFMA
    f32x16 acc[4];
#pragma unroll
    for (int cf = 0; cf < 4; ++cf) acc[cf] = (f32x16)0.0f;
#pragma unroll
    for (int cf = 0; cf < 4; ++cf)
#pragma unroll
        for (int ks = 0; ks < 4; ++ks) {
            const float* p = Bb + (size_t)(col0 + cf * 32 + lrow) * D + ks * 16 + khalf;
            float4 v0 = *(const float4*)(p);
            float4 v1 = *(const float4*)(p + 4);
            acc[cf] = __builtin_amdgcn_mfma_f32_32x32x16_bf16(
                af[ks], to_bf16x8(v0, v1), acc[cf], 0, 0, 0);
        }

    // stage acc -> LDS tile[64][256]
    // D layout (verified): C-col = lane&31, C-row = (v&3) + 8*(v>>2) + 4*(lane>>5)
#pragma unroll
    for (int cf = 0; cf < 4; ++cf) {
        const int col   = wc * 128 + cf * 32 + (lane & 31);
        const int rbase = wr * 32 + 4 * (lane >> 5);
#pragma unroll
        for (int v = 0; v < 16; ++v) {
            const int r = rbase + (v & 3) + 8 * (v >> 2);
            tile[r * 256 + col] = acc[cf][v];
        }
    }

    __syncthreads();

    // NT store sweep: each wave instruction = one full 1KB row segment
    // (64 lanes x 16B contiguous). 16 iterations cover 64 rows.
    const f32x4* t4 = (const f32x4*)tile;
    float* Cbase = Cb + (size_t)brow * N + bcol;
#pragma unroll
    for (int it = 0; it < 16; ++it) {
        const int f = it * 256 + threadIdx.x;    // float4 index in tile
        const int r = f >> 6;                    // 64 float4 per 256-col row
        const int c = f & 63;
        __builtin_nontemporal_store(t4[f], (f32x4*)(Cbase + (size_t)r * N + c * 4));
    }
}

extern "C" void kernel_launch(void* const* d_in, const int* in_sizes, int n_in,
                              void* d_out, int out_size, void* d_ws, size_t ws_size,
                              hipStream_t stream) {
    const float* m1 = (const float*)d_in[0];
    const float* m2 = (const float*)d_in[1];
    float* out = (float*)d_out;

    const int N = 4096;
    dim3 grid(N / 256, N / 64, 8);
    dim3 block(256);
    MatrixAttention_76149770158251_kernel<<<grid, block, 0, stream>>>(m1, m2, out);
}

// Round 11
// 115.132 us; speedup vs baseline: 2.2489x; 1.4367x over previous
//
#include <hip/hip_runtime.h>
#include <hip/hip_bf16.h>

typedef __attribute__((ext_vector_type(8)))  __bf16 bf16x8;
typedef __attribute__((ext_vector_type(16))) float  f32x16;
typedef __attribute__((ext_vector_type(4)))  float  f32x4;   // for nt stores

// Batched GEMM C[b] = A[b] @ B[b]^T, A/B:[8,4096,64] f32, C:[8,4096,4096] f32.
// Ledger: store shape X, run length X, occupancy X, XCD swizzle X, NT OK.
// Surviving model: TOTAL FABRIC BYTES (writes + cross-fabric read requests)
// saturate ~6.9 TB/s. R11 lever: pre-convert A,B to bf16 in d_ws -> per-block
// read bytes HALVED (64KB->32KB), everything else byte-identical to R5
// (128x128 tile, 64KB LDS staging, NT dwordx4 sweep, no swizzle).

static __device__ inline bf16x8 to_bf16x8(const float4& a, const float4& b) {
    bf16x8 r;
    r[0] = (__bf16)a.x; r[1] = (__bf16)a.y; r[2] = (__bf16)a.z; r[3] = (__bf16)a.w;
    r[4] = (__bf16)b.x; r[5] = (__bf16)b.y; r[6] = (__bf16)b.z; r[7] = (__bf16)b.w;
    return r;
}

// ---- pass 1: fp32 -> bf16 conversion (8 floats/thread, one shot)
__global__ __launch_bounds__(256) void convert_bf16_kernel(
    const float* __restrict__ in, __bf16* __restrict__ out)
{
    const int i = blockIdx.x * 256 + threadIdx.x;
    const float4 v0 = ((const float4*)in)[2 * i];
    const float4 v1 = ((const float4*)in)[2 * i + 1];
    ((bf16x8*)out)[i] = to_bf16x8(v0, v1);
}

// ---- pass 2: GEMM, reads bf16 (half the fabric read bytes of R5)
__global__ __launch_bounds__(256) void MatrixAttention_76149770158251_kernel(
    const __bf16* __restrict__ A16, const __bf16* __restrict__ B16,
    float* __restrict__ C)
{
    const int N = 4096, D = 64;
    __shared__ float tile[128 * 128];       // 64 KB C-tile staging

    const int lane = threadIdx.x & 63;
    const int wid  = threadIdx.x >> 6;      // 0..3
    const int wr   = wid >> 1;              // 2x2 wave grid
    const int wc   = wid & 1;
    const int bz   = blockIdx.z;

    const int brow = blockIdx.y * 128;
    const int bcol = blockIdx.x * 128;
    const int row0 = brow + wr * 64;
    const int col0 = bcol + wc * 64;

    const __bf16* __restrict__ Ab = A16 + (size_t)bz * N * D;
    const __bf16* __restrict__ Bb = B16 + (size_t)bz * N * D;
    float* __restrict__ Cb        = C   + (size_t)bz * N * N;

    const int lrow  = lane & 31;            // row within 32-frag
    const int khalf = (lane >> 5) * 8;      // 0 or 8: K slice

    f32x16 acc[2][2];
#pragma unroll
    for (int i = 0; i < 2; ++i)
#pragma unroll
        for (int j = 0; j < 2; ++j) acc[i][j] = (f32x16)0.0f;

#pragma unroll
    for (int ks = 0; ks < 4; ++ks) {        // K = 64 = 4 * 16
        const int k = ks * 16 + khalf;
        bf16x8 af[2], bfr[2];
#pragma unroll
        for (int rb = 0; rb < 2; ++rb)
            af[rb] = *(const bf16x8*)(Ab + (size_t)(row0 + rb * 32 + lrow) * D + k);
#pragma unroll
        for (int cb = 0; cb < 2; ++cb)
            bfr[cb] = *(const bf16x8*)(Bb + (size_t)(col0 + cb * 32 + lrow) * D + k);
#pragma unroll
        for (int rb = 0; rb < 2; ++rb)
#pragma unroll
            for (int cb = 0; cb < 2; ++cb)
                acc[rb][cb] = __builtin_amdgcn_mfma_f32_32x32x16_bf16(
                    af[rb], bfr[cb], acc[rb][cb], 0, 0, 0);
    }

    // stage acc -> LDS (verified D layout: col=lane&31, row=(v&3)+8*(v>>2)+4*(lane>>5))
#pragma unroll
    for (int rb = 0; rb < 2; ++rb)
#pragma unroll
        for (int cb = 0; cb < 2; ++cb) {
            const int col   = wc * 64 + cb * 32 + (lane & 31);
            const int rbase = wr * 64 + rb * 32 + 4 * (lane >> 5);
#pragma unroll
            for (int v = 0; v < 16; ++v) {
                const int r = rbase + (v & 3) + 8 * (v >> 2);
                tile[r * 128 + col] = acc[rb][cb][v];
            }
        }

    __syncthreads();

    // NT store sweep — byte-identical to R5 (512B runs, dwordx4, nt).
    const f32x4* t4 = (const f32x4*)tile;
    float* Cbase = Cb + (size_t)brow * N + bcol;
#pragma unroll
    for (int it = 0; it < 16; ++it) {
        const int f  = it * 256 + threadIdx.x;
        const int r  = f >> 5;
        const int cq = f & 31;
        __builtin_nontemporal_store(t4[f], (f32x4*)(Cbase + (size_t)r * N + cq * 4));
    }
}

// ---- fallback: R5 verbatim (fp32 loads) if ws too small
__global__ __launch_bounds__(256) void gemm_f32_kernel(
    const float* __restrict__ A, const float* __restrict__ Bm,
    float* __restrict__ C)
{
    const int N = 4096, D = 64;
    __shared__ float tile[128 * 128];
    const int lane = threadIdx.x & 63;
    const int wid  = threadIdx.x >> 6;
    const int wr   = wid >> 1;
    const int wc   = wid & 1;
    const int bz   = blockIdx.z;
    const int brow = blockIdx.y * 128;
    const int bcol = blockIdx.x * 128;
    const int row0 = brow + wr * 64;
    const int col0 = bcol + wc * 64;
    const float* __restrict__ Ab = A  + (size_t)bz * N * D;
    const float* __restrict__ Bb = Bm + (size_t)bz * N * D;
    float* __restrict__ Cb       = C  + (size_t)bz * N * N;
    const int lrow  = lane & 31;
    const int khalf = (lane >> 5) * 8;
    f32x16 acc[2][2];
#pragma unroll
    for (int i = 0; i < 2; ++i)
#pragma unroll
        for (int j = 0; j < 2; ++j) acc[i][j] = (f32x16)0.0f;
#pragma unroll
    for (int ks = 0; ks < 4; ++ks) {
        const int k = ks * 16 + khalf;
        bf16x8 af[2], bfr[2];
#pragma unroll
        for (int rb = 0; rb < 2; ++rb) {
            const float* p = Ab + (size_t)(row0 + rb * 32 + lrow) * D + k;
            af[rb] = to_bf16x8(*(const float4*)(p), *(const float4*)(p + 4));
        }
#pragma unroll
        for (int cb = 0; cb < 2; ++cb) {
            const float* p = Bb + (size_t)(col0 + cb * 32 + lrow) * D + k;
            bfr[cb] = to_bf16x8(*(const float4*)(p), *(const float4*)(p + 4));
        }
#pragma unroll
        for (int rb = 0; rb < 2; ++rb)
#pragma unroll
            for (int cb = 0; cb < 2; ++cb)
                acc[rb][cb] = __builtin_amdgcn_mfma_f32_32x32x16_bf16(
                    af[rb], bfr[cb], acc[rb][cb], 0, 0, 0);
    }
#pragma unroll
    for (int rb = 0; rb < 2; ++rb)
#pragma unroll
        for (int cb = 0; cb < 2; ++cb) {
            const int col   = wc * 64 + cb * 32 + (lane & 31);
            const int rbase = wr * 64 + rb * 32 + 4 * (lane >> 5);
#pragma unroll
            for (int v = 0; v < 16; ++v) {
                const int r = rbase + (v & 3) + 8 * (v >> 2);
                tile[r * 128 + col] = acc[rb][cb][v];
            }
        }
    __syncthreads();
    const f32x4* t4 = (const f32x4*)tile;
    float* Cbase = Cb + (size_t)brow * N + bcol;
#pragma unroll
    for (int it = 0; it < 16; ++it) {
        const int f  = it * 256 + threadIdx.x;
        const int r  = f >> 5;
        const int cq = f & 31;
        __builtin_nontemporal_store(t4[f], (f32x4*)(Cbase + (size_t)r * N + cq * 4));
    }
}

extern "C" void kernel_launch(void* const* d_in, const int* in_sizes, int n_in,
                              void* d_out, int out_size, void* d_ws, size_t ws_size,
                              hipStream_t stream) {
    const float* m1 = (const float*)d_in[0];
    const float* m2 = (const float*)d_in[1];
    float* out = (float*)d_out;

    const int N = 4096;
    const size_t elems = (size_t)8 * N * 64;           // 2,097,152 per tensor
    dim3 grid(N / 128, N / 128, 8);
    dim3 block(256);

    if (ws_size >= 2 * elems * sizeof(__bf16)) {
        __bf16* A16 = (__bf16*)d_ws;
        __bf16* B16 = A16 + elems;
        dim3 cgrid(elems / 8 / 256);                   // 1024 blocks
        convert_bf16_kernel<<<cgrid, block, 0, stream>>>(m1, A16);
        convert_bf16_kernel<<<cgrid, block, 0, stream>>>(m2, B16);
        MatrixAttention_76149770158251_kernel<<<grid, block, 0, stream>>>(A16, B16, out);
    } else {
        gemm_f32_kernel<<<grid, block, 0, stream>>>(m1, m2, out);
    }
}